// Round 9
// baseline (268.070 us; speedup 1.0000x reference)
//
#include <hip/hip_runtime.h>
#include <hip/hip_bf16.h>

using u16 = unsigned short;
using u32 = unsigned int;
using short8  = __attribute__((ext_vector_type(8))) short;
using short4v = __attribute__((ext_vector_type(4))) short;
using floatx4 = __attribute__((ext_vector_type(4))) float;

#define TT 2048
#define CC 1024
#define HH 16
#define DD 64
#define BBATCH 2
#define MM (BBATCH*TT)   // 4096

// (1/sqrt(64)) * log2(e): folded into Q at projection epilogue; softmax uses exp2.
#define QSCALE 0.18033688011112042f

__device__ __forceinline__ u16 f2bf(float f) {
    u32 u = __float_as_uint(f);
    u += 0x7fffu + ((u >> 16) & 1u);   // RNE
    return (u16)(u >> 16);
}
__device__ __forceinline__ float bf2f(u16 s) {
    return __uint_as_float(((u32)s) << 16);
}
// async global->LDS, 16B per lane (m97 pattern): lds dest = wave-uniform base + lane*16
__device__ __forceinline__ void gll16(const u16* g, u16* l) {
    __builtin_amdgcn_global_load_lds((const __attribute__((address_space(1))) void*)g,
                                     (__attribute__((address_space(3))) void*)l, 16, 0, 0);
}

// Split-K slot table: 40 slots/bh -> (qt, part). parts(qt) = qt/4+1, so no part
// exceeds 8 k-tiles (longest block 8 iters vs 32 unsplit). Grouped so every
// class c = slot%8 sums to exactly 34 iters (XCD-uniform under id%8 round-robin).
// entry = (qt<<2) | part ; index = (slot%8)*5 + slot/8.
__constant__ unsigned char SLOT_TBL[40] = {
    12, 28, 29, 42,  0,    // c0: (3,0)8 (7,0)8 (7,1)8 (10,2)8 (0,0)2
    44, 45, 46,  8,  4,    // c1: (11,0)8 (11,1)8 (11,2)8 (2,0)6 (1,0)4
    57, 59, 24, 20, 16,    // c2: (14,1)8 (14,3)8 (6,0)7 (5,0)6 (4,0)5
    60, 25, 37, 38, 17,    // c3: (15,0)8 (6,1)7 (9,1)7 (9,2)7 (4,1)5
    40, 41, 49, 51, 21,    // c4: (10,0)7 (10,1)7 (12,1)7 (12,3)7 (5,1)6
    52, 53, 54, 55, 33,    // c5: (13,0)7 (13,1)7 (13,2)7 (13,3)7 (8,1)6
    61, 62, 34, 36, 50,    // c6: (15,1)8 (15,2)8 (8,2)6 (9,0)6 (12,2)6
    63, 56, 58, 32, 48,    // c7: (15,3)8 (14,0)7 (14,2)7 (8,0)6 (12,0)6
};

// ---------------- fused cast fp32 -> bf16 (x + 4 weights, one launch) ----------------
__global__ __launch_bounds__(256) void cast_all(const float* __restrict__ x,
    const float* __restrict__ Wq, const float* __restrict__ Wk,
    const float* __restrict__ Wv, const float* __restrict__ Wo,
    u16* __restrict__ xb, u16* __restrict__ wqb, u16* __restrict__ wkb,
    u16* __restrict__ wvb, u16* __restrict__ wob)
{
    int i = blockIdx.x * 256 + threadIdx.x;   // 0 .. 2097151
    const float* src; u16* dst; int off;
    if (i < 1048576) { src = x; dst = xb; off = i; }
    else {
        int j = i - 1048576;
        int s = j >> 18;           // 0..3
        off = j & 262143;
        src = (s == 0) ? Wq : (s == 1) ? Wk : (s == 2) ? Wv : Wo;
        dst = (s == 0) ? wqb : (s == 1) ? wkb : (s == 2) ? wvb : wob;
    }
    float4 v = ((const float4*)src)[off];
    u16 r[4];
    r[0] = f2bf(v.x); r[1] = f2bf(v.y); r[2] = f2bf(v.z); r[3] = f2bf(v.w);
    ((ushort4*)dst)[off] = *(ushort4*)r;
}

// ---------------- qkv GEMM: 128x128 tile (m97 structure) ----------------
// z==0: Q -> [B,H,T,D] scaled by QSCALE; z==1: K -> [B,H,T,D];
// z==2: V -> vfm, frag-major global layout for attn's PV B-operand:
//   vfm[((bh*32+kt)*8 + ch)*64 + lane]*8 u16, where for chunk ch = kb*2+jd2,
//   lane ln = lqv*16+lmv: idx 0..3 = V^T[d=jd2*32+lmv][key kb*16+lqv*4+{0..3}],
//   idx 4..7 = same keys at d+16.
__global__ __launch_bounds__(256, 3) void qkv_gemm(const u16* __restrict__ xb,
    const u16* __restrict__ wq, const u16* __restrict__ wk, const u16* __restrict__ wv,
    const float* __restrict__ bq, const float* __restrict__ bk, const float* __restrict__ bv,
    u16* __restrict__ q, u16* __restrict__ k, u16* __restrict__ vfm)
{
    __shared__ u16 As[128*32];
    __shared__ u16 Bs[128*32];
    const int K = CC;
    int z = blockIdx.z;
    const u16* W = (z == 0) ? wq : (z == 1) ? wk : wv;
    const float* bias = (z == 0) ? bq : (z == 1) ? bk : bv;
    float outscale = (z == 0) ? QSCALE : 1.0f;

    int tid = threadIdx.x;
    int m0 = blockIdx.y * 128;
    int n0 = blockIdx.x * 128;
    int lane = tid & 63;
    int w  = tid >> 6;
    int wm = (w >> 1) * 64;
    int wn = (w & 1) * 64;
    int lm = lane & 15;
    int lq = lane >> 4;

    floatx4 acc[4][4];
#pragma unroll
    for (int i = 0; i < 4; ++i)
#pragma unroll
        for (int j = 0; j < 4; ++j)
            acc[i][j] = (floatx4){0.f, 0.f, 0.f, 0.f};

    const u16* ag = xb + (size_t)(m0 + (tid >> 2)) * K + (tid & 3) * 8;
    const u16* wg = W  + (size_t)(n0 + (tid >> 2)) * K + (tid & 3) * 8;
    u16* asl = As + tid * 8;
    u16* bsl = Bs + tid * 8;

    for (int k0 = 0; k0 < K; k0 += 32) {
        __syncthreads();
        gll16(ag + k0,           asl);
        gll16(ag + 64*K + k0,    asl + 2048);
        gll16(wg + k0,           bsl);
        gll16(wg + 64*K + k0,    bsl + 2048);
        __syncthreads();
        short8 af[4], bfr[4];
#pragma unroll
        for (int t = 0; t < 4; ++t) {
            af[t]  = *(const short8*)(As + (wm + t*16 + lm)*32 + lq*8);
            bfr[t] = *(const short8*)(Bs + (wn + t*16 + lm)*32 + lq*8);
        }
#pragma unroll
        for (int i = 0; i < 4; ++i)
#pragma unroll
            for (int j = 0; j < 4; ++j)
                acc[i][j] = __builtin_amdgcn_mfma_f32_16x16x32_bf16(af[i], bfr[j], acc[i][j], 0, 0, 0);
    }

    if (z < 2) {
        u16* outp = (z == 0) ? q : k;
#pragma unroll
        for (int j = 0; j < 4; ++j) {
            int col = n0 + wn + j*16 + lm;
            float bv2 = bias[col];
            int h_ = col >> 6, d_ = col & 63;
#pragma unroll
            for (int i = 0; i < 4; ++i) {
#pragma unroll
                for (int r = 0; r < 4; ++r) {
                    int row = m0 + wm + i*16 + lq*4 + r;
                    float val = (acc[i][j][r] + bv2) * outscale;
                    int b_ = row >> 11, t_ = row & (TT-1);
                    outp[(((size_t)(b_*HH + h_) * TT + t_) * DD) + d_] = f2bf(val);
                }
            }
        }
    } else {
        // V: frag-major global writes (ushort4 over 4 consecutive keys)
#pragma unroll
        for (int j = 0; j < 4; ++j) {
            int col = n0 + wn + j*16 + lm;
            float bv2 = bias[col];
            int h_ = col >> 6, d_ = col & 63;
            int ch_hi = (d_ >> 5) ;            // jd2
            int hi4   = ((d_ >> 4) & 1) * 4;
            int lmv   = d_ & 15;
#pragma unroll
            for (int i = 0; i < 4; ++i) {
                int row0 = m0 + wm + i*16 + lq*4;
                int b_ = row0 >> 11, tl = row0 & (TT-1);
                int kt = tl >> 6, kb = (tl >> 4) & 3, lqv = (tl >> 2) & 3;
                int ch = kb*2 + ch_hi;
                int lanev = lqv*16 + lmv;
                u16 rr[4];
#pragma unroll
                for (int r = 0; r < 4; ++r) rr[r] = f2bf(acc[i][j][r] + bv2);
                *(ushort4*)(vfm + ((size_t)(b_*HH + h_) * TT * DD)
                                 + (((size_t)kt*8 + ch)*64 + lanev)*8 + hi4) = *(ushort4*)rr;
            }
        }
    }
}

// ---------------- O GEMM: 128x64 tile (512 blocks, 2/CU) ----------------
__global__ __launch_bounds__(256, 4) void o_gemm(const u16* __restrict__ A, const u16* __restrict__ W,
                                                 const float* __restrict__ bias, float* __restrict__ outp)
{
    __shared__ u16 As[128*32];
    __shared__ u16 Bs[64*32];
    const int K = CC;
    int tid = threadIdx.x;
    int m0 = blockIdx.y * 128;
    int n0 = blockIdx.x * 64;
    int lane = tid & 63;
    int w  = tid >> 6;
    int lm = lane & 15;
    int lq = lane >> 4;

    floatx4 acc[2][4];
#pragma unroll
    for (int i = 0; i < 2; ++i)
#pragma unroll
        for (int j = 0; j < 4; ++j)
            acc[i][j] = (floatx4){0.f, 0.f, 0.f, 0.f};

    const u16* ag = A + (size_t)(m0 + (tid >> 2)) * K + (tid & 3) * 8;
    const u16* wg = W + (size_t)(n0 + (tid >> 2)) * K + (tid & 3) * 8;
    u16* asl = As + tid * 8;
    u16* bsl = Bs + tid * 8;

    for (int k0 = 0; k0 < K; k0 += 32) {
        __syncthreads();
        gll16(ag + k0,        asl);
        gll16(ag + 64*K + k0, asl + 2048);
        gll16(wg + k0,        bsl);
        __syncthreads();
        short8 af[2], bfr[4];
#pragma unroll
        for (int i = 0; i < 2; ++i)
            af[i] = *(const short8*)(As + (w*32 + i*16 + lm)*32 + lq*8);
#pragma unroll
        for (int j = 0; j < 4; ++j)
            bfr[j] = *(const short8*)(Bs + (j*16 + lm)*32 + lq*8);
#pragma unroll
        for (int i = 0; i < 2; ++i)
#pragma unroll
            for (int j = 0; j < 4; ++j)
                acc[i][j] = __builtin_amdgcn_mfma_f32_16x16x32_bf16(af[i], bfr[j], acc[i][j], 0, 0, 0);
    }

#pragma unroll
    for (int j = 0; j < 4; ++j) {
        int col = n0 + j*16 + lm;
        float bv2 = bias[col];
#pragma unroll
        for (int i = 0; i < 2; ++i) {
#pragma unroll
            for (int r = 0; r < 4; ++r) {
                int row = m0 + w*32 + i*16 + lq*4 + r;
                outp[(size_t)row * CC + col] = acc[i][j][r] + bv2;
            }
        }
    }
}

// ---------------- split-K MFMA flash attention (fixed-ref softmax -> additive partials) ----
// Grid (40, 32): slot -> (qt, part) via SLOT_TBL; part covers kt in [part*nkt/P, (part+1)*nkt/P),
// max 8 tiles -> critical path 8 iters (was 32). Partials: Opart bf16 [bh][qt][part][128][64],
// lpart fp32 [bh][qt][part][128]; merged by attn_finalize. K via gll16 frag-major dbuf LDS;
// V direct global->VGPR from the frag-major vfm layout (perfectly coalesced b128).
__global__ __launch_bounds__(256, 4) void attn_mfma(const u16* __restrict__ qg, const u16* __restrict__ kg,
                                                    const u16* __restrict__ vfm,
                                                    u16* __restrict__ Opart, float* __restrict__ lpart)
{
    __shared__ u16 Kf[2][8*64*8];   // 8KB per buffer

    int tid = threadIdx.x;
    int lane = tid & 63;
    int w = tid >> 6;          // wave 0..3 -> q rows w*32..+31
    int lm = lane & 15;
    int lq = lane >> 4;
    int x = blockIdx.x;        // 0..39
    int e = SLOT_TBL[(x & 7)*5 + (x >> 3)];
    int qt = e >> 2, part = e & 3;
    int P = (qt >> 2) + 1;
    int nkt = 2*qt + 2;
    int kt0 = (part*nkt)/P, kt1 = ((part+1)*nkt)/P;
    int bh = blockIdx.y;
    int q0 = qt * 128;

    const size_t basek = (size_t)bh * TT * DD;   // also vfm base (same stride)

    // Q fragments (B-operand for S^T): aq[i][ks] = Q[q0+w*32+i*16+lm][ks*32+lq*8 ..+7]
    short8 aq[2][2];
    {
        const u16* qbase = qg + basek + (size_t)(q0 + w*32 + lm) * DD + lq*8;
#pragma unroll
        for (int i = 0; i < 2; ++i)
#pragma unroll
            for (int ks = 0; ks < 2; ++ks)
                aq[i][ks] = *(const short8*)(qbase + i*16*DD + ks*32);
    }

    floatx4 oacc[2][4];
    floatx4 lacc[2];
#pragma unroll
    for (int i = 0; i < 2; ++i) {
        lacc[i] = (floatx4){0.f, 0.f, 0.f, 0.f};
#pragma unroll
        for (int j = 0; j < 4; ++j)
            oacc[i][j] = (floatx4){0.f, 0.f, 0.f, 0.f};
    }
    short4v ones;
#pragma unroll
    for (int j = 0; j < 4; ++j) ones[j] = (short)0x3F80;   // bf16 1.0

    // K async staging: wave w stages chunks (w*2+ks); per lane row kbase+w*16+lm, col ks*32+lq*8
    const u16* kgl = kg + basek + (size_t)(w*16 + lm) * DD + lq*8;
    int wrowmax = q0 + w*32 + 31;

    // prologue: stage kt0 into buf 0
    {
        const u16* kn = kgl + (size_t)kt0*64*DD;
        gll16(kn,      &Kf[0][(w*2+0)*512] + lane*8);
        gll16(kn + 32, &Kf[0][(w*2+1)*512] + lane*8);
    }

    for (int kt = kt0; kt < kt1; ++kt) {
        int p = (kt - kt0) & 1;
        __syncthreads();   // drains gll16(kt); prior reads of buf[1-p] complete
        if (kt + 1 < kt1) {
            const u16* kn = kgl + (size_t)(kt+1)*64*DD;
            gll16(kn,      &Kf[1-p][(w*2+0)*512] + lane*8);
            gll16(kn + 32, &Kf[1-p][(w*2+1)*512] + lane*8);
        }

        int kbase = kt * 64;
        if (kbase <= wrowmax) {
            // V chunks: direct coalesced global loads (frag-major layout)
            short8 vchunk[8];
            {
                const u16* vb = vfm + basek + ((size_t)kt*8*64 + lane)*8;
#pragma unroll
                for (int ch = 0; ch < 8; ++ch)
                    vchunk[ch] = *(const short8*)(vb + ch*512);
            }

            // ---- S^T = K Q^T : col=lm -> q, row=lq*4+r -> key ----
            short8 kf[4][2];
#pragma unroll
            for (int jn = 0; jn < 4; ++jn)
#pragma unroll
                for (int ks = 0; ks < 2; ++ks)
                    kf[jn][ks] = *(const short8*)(&Kf[p][(jn*2+ks)*512] + lane*8);

            floatx4 st[2][4];
#pragma unroll
            for (int i = 0; i < 2; ++i)
#pragma unroll
                for (int jn = 0; jn < 4; ++jn)
                    st[i][jn] = (floatx4){0.f, 0.f, 0.f, 0.f};
#pragma unroll
            for (int jn = 0; jn < 4; ++jn)
#pragma unroll
                for (int i = 0; i < 2; ++i) {
                    st[i][jn] = __builtin_amdgcn_mfma_f32_16x16x32_bf16(kf[jn][0], aq[i][0], st[i][jn], 0, 0, 0);
                    st[i][jn] = __builtin_amdgcn_mfma_f32_16x16x32_bf16(kf[jn][1], aq[i][1], st[i][jn], 0, 0, 0);
                }

            // ---- P = exp2(S) (fixed-reference softmax; masked -> exp2(-inf)=0) ----
            short4v ap[2][4];
#pragma unroll
            for (int i = 0; i < 2; ++i) {
                int qrow = q0 + w*32 + i*16 + lm;
                if (kbase + 63 > q0 + w*32 + i*16) {   // diagonal tiles only
#pragma unroll
                    for (int jn = 0; jn < 4; ++jn)
#pragma unroll
                        for (int r = 0; r < 4; ++r) {
                            int key = kbase + jn*16 + lq*4 + r;
                            if (key > qrow) st[i][jn][r] = -__builtin_inff();
                        }
                }
#pragma unroll
                for (int jn = 0; jn < 4; ++jn) {
#pragma unroll
                    for (int r = 0; r < 4; ++r)
                        st[i][jn][r] = __builtin_amdgcn_exp2f(st[i][jn][r]);
                    u32 lo = __builtin_amdgcn_perm(__float_as_uint(st[i][jn][1]),
                                                   __float_as_uint(st[i][jn][0]), 0x07060302u);
                    u32 hi = __builtin_amdgcn_perm(__float_as_uint(st[i][jn][3]),
                                                   __float_as_uint(st[i][jn][2]), 0x07060302u);
                    uint2 pk = make_uint2(lo, hi);
                    ap[i][jn] = __builtin_bit_cast(short4v, pk);
                }
            }

            // ---- O += P V ; l += P·1 via ones-MFMA ----
#pragma unroll
            for (int kb = 0; kb < 4; ++kb) {
#pragma unroll
                for (int jd2 = 0; jd2 < 2; ++jd2) {
                    short8 vv = vchunk[kb*2 + jd2];
                    short4v vlo, vhi;
#pragma unroll
                    for (int j = 0; j < 4; ++j) { vlo[j] = vv[j]; vhi[j] = vv[j+4]; }
#pragma unroll
                    for (int i = 0; i < 2; ++i) {
                        oacc[i][jd2*2]   = __builtin_amdgcn_mfma_f32_16x16x16bf16_1k(ap[i][kb], vlo, oacc[i][jd2*2],   0, 0, 0);
                        oacc[i][jd2*2+1] = __builtin_amdgcn_mfma_f32_16x16x16bf16_1k(ap[i][kb], vhi, oacc[i][jd2*2+1], 0, 0, 0);
                    }
                }
#pragma unroll
                for (int i = 0; i < 2; ++i)
                    lacc[i] = __builtin_amdgcn_mfma_f32_16x16x16bf16_1k(ap[i][kb], ones, lacc[i], 0, 0, 0);
            }
        }
    }

    // ---- epilogue: write partials (unconditional — skipped waves write zeros) ----
    size_t slot = (size_t)(bh*16 + qt)*4 + part;
    u16* obase = Opart + slot * (128*64);
#pragma unroll
    for (int i = 0; i < 2; ++i) {
#pragma unroll
        for (int r = 0; r < 4; ++r) {
            int row = w*32 + i*16 + lq*4 + r;
#pragma unroll
            for (int jd = 0; jd < 4; ++jd)
                obase[row*64 + jd*16 + lm] = f2bf(oacc[i][jd][r]);
            if (lm == 0)
                lpart[slot*128 + row] = lacc[i][r];
        }
    }
}

// ---------------- merge partials, normalize, write attnb [B,T,C] bf16 ----------------
__global__ __launch_bounds__(256) void attn_finalize(const u16* __restrict__ Opart,
    const float* __restrict__ lpart, u16* __restrict__ attnb)
{
    int qt = blockIdx.x, bh = blockIdx.y;
    int b_ = bh >> 4, h_ = bh & 15;
    int P = (qt >> 2) + 1;
    int tid = threadIdx.x;
    __shared__ float lt[128];
    size_t slot0 = (size_t)(bh*16 + qt)*4;
    if (tid < 128) {
        float s = 0.f;
        for (int p2 = 0; p2 < P; ++p2) s += lpart[(slot0 + p2)*128 + tid];
        lt[tid] = 1.f / s;
    }
    __syncthreads();
#pragma unroll
    for (int jj = 0; jj < 8; ++jj) {
        int e4 = tid + jj*256;        // ushort4 index 0..2047
        int ei = e4 * 4;
        int row = ei >> 6, d = ei & 63;
        float a0 = 0.f, a1 = 0.f, a2 = 0.f, a3 = 0.f;
        for (int p2 = 0; p2 < P; ++p2) {
            ushort4 v = *(const ushort4*)(Opart + (slot0 + p2)*8192 + ei);
            a0 += bf2f(v.x); a1 += bf2f(v.y); a2 += bf2f(v.z); a3 += bf2f(v.w);
        }
        float il = lt[row];
        u16 rr[4] = {f2bf(a0*il), f2bf(a1*il), f2bf(a2*il), f2bf(a3*il)};
        *(ushort4*)(attnb + ((size_t)(b_*TT + qt*128 + row))*CC + h_*DD + d) = *(ushort4*)rr;
    }
}

extern "C" void kernel_launch(void* const* d_in, const int* in_sizes, int n_in,
                              void* d_out, int out_size, void* d_ws, size_t ws_size,
                              hipStream_t stream)
{
    const float* x  = (const float*)d_in[0];
    const float* Wq = (const float*)d_in[1];
    const float* bq = (const float*)d_in[2];
    const float* Wk = (const float*)d_in[3];
    const float* bk = (const float*)d_in[4];
    const float* Wv = (const float*)d_in[5];
    const float* bv = (const float*)d_in[6];
    const float* Wo = (const float*)d_in[7];
    const float* bo = (const float*)d_in[8];
    float* out = (float*)d_out;

    char* ws = (char*)d_ws;
    u16*   xb    = (u16*)(ws);                      // 8 MB (reused as attnb)
    u16*   wqb   = (u16*)(ws + (size_t)( 8<<20));
    u16*   wkb   = (u16*)(ws + (size_t)(10<<20));
    u16*   wvb   = (u16*)(ws + (size_t)(12<<20));
    u16*   wob   = (u16*)(ws + (size_t)(14<<20));
    u16*   q     = (u16*)(ws + (size_t)(16<<20));   // [B,H,T,D], pre-scaled
    u16*   k     = (u16*)(ws + (size_t)(24<<20));   // [B,H,T,D]
    u16*   vfm   = (u16*)(ws + (size_t)(32<<20));   // frag-major V, 8 MB
    u16*   Opart = (u16*)(ws + (size_t)(40<<20));   // bf16 partials, 32 MB
    float* lpart = (float*)(ws + (size_t)(72<<20)); // fp32 partials, 1 MB
    u16*   attnb = xb;                              // xb dead after qkv_gemm

    cast_all<<<dim3(8192), dim3(256), 0, stream>>>(x, Wq, Wk, Wv, Wo, xb, wqb, wkb, wvb, wob);

    dim3 gq(CC/128, MM/128, 3);
    qkv_gemm<<<gq, dim3(256), 0, stream>>>(xb, wqb, wkb, wvb, bq, bk, bv, q, k, vfm);

    attn_mfma<<<dim3(40, BBATCH*HH), dim3(256), 0, stream>>>(q, k, vfm, Opart, lpart);

    attn_finalize<<<dim3(16, BBATCH*HH), dim3(256), 0, stream>>>(Opart, lpart, attnb);

    dim3 go(CC/64, MM/128);
    o_gemm<<<go, dim3(256), 0, stream>>>(attnb, wob, bo, out);
}

// Round 10
// 186.046 us; speedup vs baseline: 1.4409x; 1.4409x over previous
//
#include <hip/hip_runtime.h>
#include <hip/hip_bf16.h>

using u16 = unsigned short;
using u32 = unsigned int;
using short8  = __attribute__((ext_vector_type(8))) short;
using short4v = __attribute__((ext_vector_type(4))) short;
using floatx4 = __attribute__((ext_vector_type(4))) float;

#define TT 2048
#define CC 1024
#define HH 16
#define DD 64
#define BBATCH 2
#define MM (BBATCH*TT)   // 4096

// (1/sqrt(64)) * log2(e): folded into Q at projection epilogue; softmax uses exp2.
#define QSCALE 0.18033688011112042f

__device__ __forceinline__ u16 f2bf(float f) {
    u32 u = __float_as_uint(f);
    u += 0x7fffu + ((u >> 16) & 1u);   // RNE
    return (u16)(u >> 16);
}
__device__ __forceinline__ float bf2f(u16 s) {
    return __uint_as_float(((u32)s) << 16);
}
// async global->LDS, 16B per lane (m97 pattern): lds dest = wave-uniform base + lane*16
__device__ __forceinline__ void gll16(const u16* g, u16* l) {
    __builtin_amdgcn_global_load_lds((const __attribute__((address_space(1))) void*)g,
                                     (__attribute__((address_space(3))) void*)l, 16, 0, 0);
}

// Split-K slot table: 40 slots/bh -> (qt, part). parts(qt) = qt/4+1, so no part
// exceeds 8 k-tiles (longest block 8 iters vs 32 unsplit). Grouped so every
// class c = slot%8 sums to exactly 34 iters (XCD-uniform under id%8 round-robin).
// entry = (qt<<2) | part ; index = (slot%8)*5 + slot/8.
__constant__ unsigned char SLOT_TBL[40] = {
    12, 28, 29, 42,  0,    // c0: (3,0)8 (7,0)8 (7,1)8 (10,2)8 (0,0)2
    44, 45, 46,  8,  4,    // c1: (11,0)8 (11,1)8 (11,2)8 (2,0)6 (1,0)4
    57, 59, 24, 20, 16,    // c2: (14,1)8 (14,3)8 (6,0)7 (5,0)6 (4,0)5
    60, 25, 37, 38, 17,    // c3: (15,0)8 (6,1)7 (9,1)7 (9,2)7 (4,1)5
    40, 41, 49, 51, 21,    // c4: (10,0)7 (10,1)7 (12,1)7 (12,3)7 (5,1)6
    52, 53, 54, 55, 33,    // c5: (13,0)7 (13,1)7 (13,2)7 (13,3)7 (8,1)6
    61, 62, 34, 36, 50,    // c6: (15,1)8 (15,2)8 (8,2)6 (9,0)6 (12,2)6
    63, 56, 58, 32, 48,    // c7: (15,3)8 (14,0)7 (14,2)7 (8,0)6 (12,0)6
};

// ---------------- fused cast fp32 -> bf16 (x + 4 weights, one launch) ----------------
__global__ __launch_bounds__(256) void cast_all(const float* __restrict__ x,
    const float* __restrict__ Wq, const float* __restrict__ Wk,
    const float* __restrict__ Wv, const float* __restrict__ Wo,
    u16* __restrict__ xb, u16* __restrict__ wqb, u16* __restrict__ wkb,
    u16* __restrict__ wvb, u16* __restrict__ wob)
{
    int i = blockIdx.x * 256 + threadIdx.x;   // 0 .. 2097151
    const float* src; u16* dst; int off;
    if (i < 1048576) { src = x; dst = xb; off = i; }
    else {
        int j = i - 1048576;
        int s = j >> 18;           // 0..3
        off = j & 262143;
        src = (s == 0) ? Wq : (s == 1) ? Wk : (s == 2) ? Wv : Wo;
        dst = (s == 0) ? wqb : (s == 1) ? wkb : (s == 2) ? wvb : wob;
    }
    float4 v = ((const float4*)src)[off];
    u16 r[4];
    r[0] = f2bf(v.x); r[1] = f2bf(v.y); r[2] = f2bf(v.z); r[3] = f2bf(v.w);
    ((ushort4*)dst)[off] = *(ushort4*)r;
}

// ---------------- qkv GEMM: 128x128 tile (m97 structure) ----------------
// z==0: Q -> [B,H,T,D] scaled by QSCALE; z==1: K -> [B,H,T,D];
// z==2: V -> vfm, frag-major global layout for attn's PV B-operand:
//   vfm[((bh*32+kt)*8 + ch)*64 + lane]*8 u16, where for chunk ch = kb*2+jd2,
//   lane ln = lqv*16+lmv: idx 0..3 = V^T[d=jd2*32+lmv][key kb*16+lqv*4+{0..3}],
//   idx 4..7 = same keys at d+16.
__global__ __launch_bounds__(256, 3) void qkv_gemm(const u16* __restrict__ xb,
    const u16* __restrict__ wq, const u16* __restrict__ wk, const u16* __restrict__ wv,
    const float* __restrict__ bq, const float* __restrict__ bk, const float* __restrict__ bv,
    u16* __restrict__ q, u16* __restrict__ k, u16* __restrict__ vfm)
{
    __shared__ u16 As[128*32];
    __shared__ u16 Bs[128*32];
    const int K = CC;
    int z = blockIdx.z;
    const u16* W = (z == 0) ? wq : (z == 1) ? wk : wv;
    const float* bias = (z == 0) ? bq : (z == 1) ? bk : bv;
    float outscale = (z == 0) ? QSCALE : 1.0f;

    int tid = threadIdx.x;
    int m0 = blockIdx.y * 128;
    int n0 = blockIdx.x * 128;
    int lane = tid & 63;
    int w  = tid >> 6;
    int wm = (w >> 1) * 64;
    int wn = (w & 1) * 64;
    int lm = lane & 15;
    int lq = lane >> 4;

    floatx4 acc[4][4];
#pragma unroll
    for (int i = 0; i < 4; ++i)
#pragma unroll
        for (int j = 0; j < 4; ++j)
            acc[i][j] = (floatx4){0.f, 0.f, 0.f, 0.f};

    const u16* ag = xb + (size_t)(m0 + (tid >> 2)) * K + (tid & 3) * 8;
    const u16* wg = W  + (size_t)(n0 + (tid >> 2)) * K + (tid & 3) * 8;
    u16* asl = As + tid * 8;
    u16* bsl = Bs + tid * 8;

    for (int k0 = 0; k0 < K; k0 += 32) {
        __syncthreads();
        gll16(ag + k0,           asl);
        gll16(ag + 64*K + k0,    asl + 2048);
        gll16(wg + k0,           bsl);
        gll16(wg + 64*K + k0,    bsl + 2048);
        __syncthreads();
        short8 af[4], bfr[4];
#pragma unroll
        for (int t = 0; t < 4; ++t) {
            af[t]  = *(const short8*)(As + (wm + t*16 + lm)*32 + lq*8);
            bfr[t] = *(const short8*)(Bs + (wn + t*16 + lm)*32 + lq*8);
        }
#pragma unroll
        for (int i = 0; i < 4; ++i)
#pragma unroll
            for (int j = 0; j < 4; ++j)
                acc[i][j] = __builtin_amdgcn_mfma_f32_16x16x32_bf16(af[i], bfr[j], acc[i][j], 0, 0, 0);
    }

    if (z < 2) {
        u16* outp = (z == 0) ? q : k;
#pragma unroll
        for (int j = 0; j < 4; ++j) {
            int col = n0 + wn + j*16 + lm;
            float bv2 = bias[col];
            int h_ = col >> 6, d_ = col & 63;
#pragma unroll
            for (int i = 0; i < 4; ++i) {
#pragma unroll
                for (int r = 0; r < 4; ++r) {
                    int row = m0 + wm + i*16 + lq*4 + r;
                    float val = (acc[i][j][r] + bv2) * outscale;
                    int b_ = row >> 11, t_ = row & (TT-1);
                    outp[(((size_t)(b_*HH + h_) * TT + t_) * DD) + d_] = f2bf(val);
                }
            }
        }
    } else {
        // V: frag-major global writes (ushort4 over 4 consecutive keys)
#pragma unroll
        for (int j = 0; j < 4; ++j) {
            int col = n0 + wn + j*16 + lm;
            float bv2 = bias[col];
            int h_ = col >> 6, d_ = col & 63;
            int ch_hi = (d_ >> 5);             // jd2
            int hi4   = ((d_ >> 4) & 1) * 4;
            int lmv   = d_ & 15;
#pragma unroll
            for (int i = 0; i < 4; ++i) {
                int row0 = m0 + wm + i*16 + lq*4;
                int b_ = row0 >> 11, tl = row0 & (TT-1);
                int kt = tl >> 6, kb = (tl >> 4) & 3, lqv = (tl >> 2) & 3;
                int ch = kb*2 + ch_hi;
                int lanev = lqv*16 + lmv;
                u16 rr[4];
#pragma unroll
                for (int r = 0; r < 4; ++r) rr[r] = f2bf(acc[i][j][r] + bv2);
                *(ushort4*)(vfm + ((size_t)(b_*HH + h_) * TT * DD)
                                 + (((size_t)kt*8 + ch)*64 + lanev)*8 + hi4) = *(ushort4*)rr;
            }
        }
    }
}

// ---------------- O GEMM: 128x64 tile (512 blocks, 2/CU) ----------------
__global__ __launch_bounds__(256, 4) void o_gemm(const u16* __restrict__ A, const u16* __restrict__ W,
                                                 const float* __restrict__ bias, float* __restrict__ outp)
{
    __shared__ u16 As[128*32];
    __shared__ u16 Bs[64*32];
    const int K = CC;
    int tid = threadIdx.x;
    int m0 = blockIdx.y * 128;
    int n0 = blockIdx.x * 64;
    int lane = tid & 63;
    int w  = tid >> 6;
    int lm = lane & 15;
    int lq = lane >> 4;

    floatx4 acc[2][4];
#pragma unroll
    for (int i = 0; i < 2; ++i)
#pragma unroll
        for (int j = 0; j < 4; ++j)
            acc[i][j] = (floatx4){0.f, 0.f, 0.f, 0.f};

    const u16* ag = A + (size_t)(m0 + (tid >> 2)) * K + (tid & 3) * 8;
    const u16* wg = W + (size_t)(n0 + (tid >> 2)) * K + (tid & 3) * 8;
    u16* asl = As + tid * 8;
    u16* bsl = Bs + tid * 8;

    for (int k0 = 0; k0 < K; k0 += 32) {
        __syncthreads();
        gll16(ag + k0,        asl);
        gll16(ag + 64*K + k0, asl + 2048);
        gll16(wg + k0,        bsl);
        __syncthreads();
        short8 af[2], bfr[4];
#pragma unroll
        for (int i = 0; i < 2; ++i)
            af[i] = *(const short8*)(As + (w*32 + i*16 + lm)*32 + lq*8);
#pragma unroll
        for (int j = 0; j < 4; ++j)
            bfr[j] = *(const short8*)(Bs + (j*16 + lm)*32 + lq*8);
#pragma unroll
        for (int i = 0; i < 2; ++i)
#pragma unroll
            for (int j = 0; j < 4; ++j)
                acc[i][j] = __builtin_amdgcn_mfma_f32_16x16x32_bf16(af[i], bfr[j], acc[i][j], 0, 0, 0);
    }

#pragma unroll
    for (int j = 0; j < 4; ++j) {
        int col = n0 + j*16 + lm;
        float bv2 = bias[col];
#pragma unroll
        for (int i = 0; i < 2; ++i) {
#pragma unroll
            for (int r = 0; r < 4; ++r) {
                int row = m0 + w*32 + i*16 + lq*4 + r;
                outp[(size_t)row * CC + col] = acc[i][j][r] + bv2;
            }
        }
    }
}

// ---------------- split-K MFMA flash attention, traffic-fixed ----------------
// Grid (40, 32): slot -> (qt, part) via SLOT_TBL; max 8 k-tiles per block.
// K AND V staged via gll16 into frag-major dbuf LDS (shared by all 4 waves —
// R9 loaded V per-wave from global = 4x redundant traffic). Partials written
// frag-major, lane-contiguous uint2 (fully-written cachelines — R9's scattered
// 2B stores caused ~6x write amplification, WRITE_SIZE 207 MB vs 33 logical).
__global__ __launch_bounds__(256, 4) void attn_mfma(const u16* __restrict__ qg, const u16* __restrict__ kg,
                                                    const u16* __restrict__ vfm,
                                                    u16* __restrict__ Opart, float* __restrict__ lpart)
{
    __shared__ u16 Kf[2][8*64*8];   // 8KB per buffer
    __shared__ u16 Vf[2][8*64*8];   // 8KB per buffer

    int tid = threadIdx.x;
    int lane = tid & 63;
    int w = tid >> 6;          // wave 0..3 -> q rows w*32..+31
    int lm = lane & 15;
    int lq = lane >> 4;
    int x = blockIdx.x;        // 0..39
    int e = SLOT_TBL[(x & 7)*5 + (x >> 3)];
    int qt = e >> 2, part = e & 3;
    int P = (qt >> 2) + 1;
    int nkt = 2*qt + 2;
    int kt0 = (part*nkt)/P, kt1 = ((part+1)*nkt)/P;
    int bh = blockIdx.y;
    int q0 = qt * 128;

    const size_t basek = (size_t)bh * TT * DD;   // also vfm base (same stride)

    // Q fragments (B-operand for S^T): aq[i][ks] = Q[q0+w*32+i*16+lm][ks*32+lq*8 ..+7]
    short8 aq[2][2];
    {
        const u16* qbase = qg + basek + (size_t)(q0 + w*32 + lm) * DD + lq*8;
#pragma unroll
        for (int i = 0; i < 2; ++i)
#pragma unroll
            for (int ks = 0; ks < 2; ++ks)
                aq[i][ks] = *(const short8*)(qbase + i*16*DD + ks*32);
    }

    floatx4 oacc[2][4];
    floatx4 lacc[2];
#pragma unroll
    for (int i = 0; i < 2; ++i) {
        lacc[i] = (floatx4){0.f, 0.f, 0.f, 0.f};
#pragma unroll
        for (int j = 0; j < 4; ++j)
            oacc[i][j] = (floatx4){0.f, 0.f, 0.f, 0.f};
    }
    short4v ones;
#pragma unroll
    for (int j = 0; j < 4; ++j) ones[j] = (short)0x3F80;   // bf16 1.0

    // staging: wave w stages K chunks (w*2+c) and V chunks (w*2+c), c=0,1
    const u16* kgl = kg  + basek + (size_t)(w*16 + lm) * DD + lq*8;   // + kt*64*DD + c*32
    const u16* vgl = vfm + basek + lane*8;                            // + ((kt*8 + w*2+c))*512
    int wrowmax = q0 + w*32 + 31;

    // prologue: stage kt0 into buf 0
    {
        const u16* kn = kgl + (size_t)kt0*64*DD;
        const u16* vn = vgl + (size_t)kt0*8*512;
        gll16(kn,                  &Kf[0][(w*2+0)*512] + lane*8);
        gll16(kn + 32,             &Kf[0][(w*2+1)*512] + lane*8);
        gll16(vn + (w*2+0)*512,    &Vf[0][(w*2+0)*512] + lane*8);
        gll16(vn + (w*2+1)*512,    &Vf[0][(w*2+1)*512] + lane*8);
    }

    for (int kt = kt0; kt < kt1; ++kt) {
        int p = (kt - kt0) & 1;
        __syncthreads();   // drains gll16(kt); prior reads of buf[1-p] complete
        if (kt + 1 < kt1) {
            const u16* kn = kgl + (size_t)(kt+1)*64*DD;
            const u16* vn = vgl + (size_t)(kt+1)*8*512;
            gll16(kn,               &Kf[1-p][(w*2+0)*512] + lane*8);
            gll16(kn + 32,          &Kf[1-p][(w*2+1)*512] + lane*8);
            gll16(vn + (w*2+0)*512, &Vf[1-p][(w*2+0)*512] + lane*8);
            gll16(vn + (w*2+1)*512, &Vf[1-p][(w*2+1)*512] + lane*8);
        }

        int kbase = kt * 64;
        if (kbase <= wrowmax) {
            // ---- S^T = K Q^T : col=lm -> q, row=lq*4+r -> key ----
            short8 kf[4][2];
#pragma unroll
            for (int jn = 0; jn < 4; ++jn)
#pragma unroll
                for (int ks = 0; ks < 2; ++ks)
                    kf[jn][ks] = *(const short8*)(&Kf[p][(jn*2+ks)*512] + lane*8);

            floatx4 st[2][4];
#pragma unroll
            for (int i = 0; i < 2; ++i)
#pragma unroll
                for (int jn = 0; jn < 4; ++jn)
                    st[i][jn] = (floatx4){0.f, 0.f, 0.f, 0.f};
#pragma unroll
            for (int jn = 0; jn < 4; ++jn)
#pragma unroll
                for (int i = 0; i < 2; ++i) {
                    st[i][jn] = __builtin_amdgcn_mfma_f32_16x16x32_bf16(kf[jn][0], aq[i][0], st[i][jn], 0, 0, 0);
                    st[i][jn] = __builtin_amdgcn_mfma_f32_16x16x32_bf16(kf[jn][1], aq[i][1], st[i][jn], 0, 0, 0);
                }

            // ---- P = exp2(S) (fixed-reference softmax; masked -> exp2(-inf)=0) ----
            short4v ap[2][4];
#pragma unroll
            for (int i = 0; i < 2; ++i) {
                int qrow = q0 + w*32 + i*16 + lm;
                if (kbase + 63 > q0 + w*32 + i*16) {   // diagonal tiles only
#pragma unroll
                    for (int jn = 0; jn < 4; ++jn)
#pragma unroll
                        for (int r = 0; r < 4; ++r) {
                            int key = kbase + jn*16 + lq*4 + r;
                            if (key > qrow) st[i][jn][r] = -__builtin_inff();
                        }
                }
#pragma unroll
                for (int jn = 0; jn < 4; ++jn) {
#pragma unroll
                    for (int r = 0; r < 4; ++r)
                        st[i][jn][r] = __builtin_amdgcn_exp2f(st[i][jn][r]);
                    u32 lo = __builtin_amdgcn_perm(__float_as_uint(st[i][jn][1]),
                                                   __float_as_uint(st[i][jn][0]), 0x07060302u);
                    u32 hi = __builtin_amdgcn_perm(__float_as_uint(st[i][jn][3]),
                                                   __float_as_uint(st[i][jn][2]), 0x07060302u);
                    uint2 pk = make_uint2(lo, hi);
                    ap[i][jn] = __builtin_bit_cast(short4v, pk);
                }
            }

            // ---- O += P V ; l += P·1 via ones-MFMA ----
#pragma unroll
            for (int kb = 0; kb < 4; ++kb) {
#pragma unroll
                for (int jd2 = 0; jd2 < 2; ++jd2) {
                    short8 vv = *(const short8*)(&Vf[p][(kb*2+jd2)*512] + lane*8);
                    short4v vlo, vhi;
#pragma unroll
                    for (int j = 0; j < 4; ++j) { vlo[j] = vv[j]; vhi[j] = vv[j+4]; }
#pragma unroll
                    for (int i = 0; i < 2; ++i) {
                        oacc[i][jd2*2]   = __builtin_amdgcn_mfma_f32_16x16x16bf16_1k(ap[i][kb], vlo, oacc[i][jd2*2],   0, 0, 0);
                        oacc[i][jd2*2+1] = __builtin_amdgcn_mfma_f32_16x16x16bf16_1k(ap[i][kb], vhi, oacc[i][jd2*2+1], 0, 0, 0);
                    }
                }
#pragma unroll
                for (int i = 0; i < 2; ++i)
                    lacc[i] = __builtin_amdgcn_mfma_f32_16x16x16bf16_1k(ap[i][kb], ones, lacc[i], 0, 0, 0);
            }
        }
    }

    // ---- epilogue: frag-major coalesced partials (uint2 per lane = 512B/instr) ----
    size_t slot = (size_t)(bh*16 + qt)*4 + part;
    u16* obase = Opart + slot * 8192;
#pragma unroll
    for (int i = 0; i < 2; ++i) {
#pragma unroll
        for (int jd = 0; jd < 4; ++jd) {
            u32 lo = (u32)f2bf(oacc[i][jd][0]) | ((u32)f2bf(oacc[i][jd][1]) << 16);
            u32 hi = (u32)f2bf(oacc[i][jd][2]) | ((u32)f2bf(oacc[i][jd][3]) << 16);
            *(uint2*)(obase + ((w*8 + i*4 + jd)*64 + lane)*4) = make_uint2(lo, hi);
        }
#pragma unroll
        for (int r = 0; r < 4; ++r)
            if (lm == 0)
                lpart[slot*128 + w*32 + i*16 + lq*4 + r] = lacc[i][r];
    }
}

// ---------------- merge partials (frag-major coalesced reads), normalize, write attnb ----
__global__ __launch_bounds__(256) void attn_finalize(const u16* __restrict__ Opart,
    const float* __restrict__ lpart, u16* __restrict__ attnb)
{
    int qt = blockIdx.x, bh = blockIdx.y;
    int b_ = bh >> 4, h_ = bh & 15;
    int P = (qt >> 2) + 1;
    int tid = threadIdx.x;
    int lane = tid & 63, w = tid >> 6, lm = lane & 15, lq = lane >> 4;
    __shared__ float lt[128];
    size_t slot0 = (size_t)(bh*16 + qt)*4;
    if (tid < 128) {
        float s = 0.f;
        for (int p2 = 0; p2 < P; ++p2) s += lpart[(slot0 + p2)*128 + tid];
        lt[tid] = 1.f / s;
    }
    __syncthreads();
#pragma unroll
    for (int i = 0; i < 2; ++i) {
        float acc[4][4] = {};   // [jd][r]
        for (int p2 = 0; p2 < P; ++p2) {
            const u16* ob = Opart + (slot0 + p2)*8192;
#pragma unroll
            for (int jd = 0; jd < 4; ++jd) {
                uint2 v = *(const uint2*)(ob + ((w*8 + i*4 + jd)*64 + lane)*4);
                acc[jd][0] += bf2f((u16)(v.x & 0xffff));
                acc[jd][1] += bf2f((u16)(v.x >> 16));
                acc[jd][2] += bf2f((u16)(v.y & 0xffff));
                acc[jd][3] += bf2f((u16)(v.y >> 16));
            }
        }
#pragma unroll
        for (int r = 0; r < 4; ++r) {
            int row = w*32 + i*16 + lq*4 + r;
            float il = lt[row];
            u16* orow = attnb + ((size_t)(b_*TT + qt*128 + row))*CC + h_*DD + lm;
#pragma unroll
            for (int jd = 0; jd < 4; ++jd)
                orow[jd*16] = f2bf(acc[jd][r] * il);
        }
    }
}

extern "C" void kernel_launch(void* const* d_in, const int* in_sizes, int n_in,
                              void* d_out, int out_size, void* d_ws, size_t ws_size,
                              hipStream_t stream)
{
    const float* x  = (const float*)d_in[0];
    const float* Wq = (const float*)d_in[1];
    const float* bq = (const float*)d_in[2];
    const float* Wk = (const float*)d_in[3];
    const float* bk = (const float*)d_in[4];
    const float* Wv = (const float*)d_in[5];
    const float* bv = (const float*)d_in[6];
    const float* Wo = (const float*)d_in[7];
    const float* bo = (const float*)d_in[8];
    float* out = (float*)d_out;

    char* ws = (char*)d_ws;
    u16*   xb    = (u16*)(ws);                      // 8 MB (reused as attnb)
    u16*   wqb   = (u16*)(ws + (size_t)( 8<<20));
    u16*   wkb   = (u16*)(ws + (size_t)(10<<20));
    u16*   wvb   = (u16*)(ws + (size_t)(12<<20));
    u16*   wob   = (u16*)(ws + (size_t)(14<<20));
    u16*   q     = (u16*)(ws + (size_t)(16<<20));   // [B,H,T,D], pre-scaled
    u16*   k     = (u16*)(ws + (size_t)(24<<20));   // [B,H,T,D]
    u16*   vfm   = (u16*)(ws + (size_t)(32<<20));   // frag-major V, 8 MB
    u16*   Opart = (u16*)(ws + (size_t)(40<<20));   // bf16 partials, 32 MB
    float* lpart = (float*)(ws + (size_t)(72<<20)); // fp32 partials, 1 MB
    u16*   attnb = xb;                              // xb dead after qkv_gemm

    cast_all<<<dim3(8192), dim3(256), 0, stream>>>(x, Wq, Wk, Wv, Wo, xb, wqb, wkb, wvb, wob);

    dim3 gq(CC/128, MM/128, 3);
    qkv_gemm<<<gq, dim3(256), 0, stream>>>(xb, wqb, wkb, wvb, bq, bk, bv, q, k, vfm);

    attn_mfma<<<dim3(40, BBATCH*HH), dim3(256), 0, stream>>>(q, k, vfm, Opart, lpart);

    attn_finalize<<<dim3(16, BBATCH*HH), dim3(256), 0, stream>>>(Opart, lpart, attnb);

    dim3 go(CC/64, MM/128);
    o_gemm<<<go, dim3(256), 0, stream>>>(attnb, wob, bo, out);
}